// Round 7
// baseline (180.464 us; speedup 1.0000x reference)
//
#include <hip/hip_runtime.h>

#define BB 16
#define TT 8192
#define NN 128                     // N_PRE == N_POST
constexpr int CHUNK = 256;         // time-steps per block (1 chunk per block)
constexpr int NBLK  = BB * TT / CHUNK;   // 512 blocks -> 2 blocks/CU
constexpr int OUTN  = NN * NN;           // 16384
constexpr int GS    = 260;         // bufG row stride in halves (520 B, 8B-aligned)
constexpr int SLOTS = OUTN / 2;    // 8192 packed u32 slots per block-slice
constexpr int NWAVE = 8;           // 512 threads
constexpr int WIN   = CHUNK / NWAVE;     // 32-step filter window per wave

typedef _Float16 f16x8 __attribute__((ext_vector_type(8)));
typedef _Float16 f16x2 __attribute__((ext_vector_type(2)));
typedef float    f32x4 __attribute__((ext_vector_type(4)));

__device__ __forceinline__ unsigned short h16(float x) {
    _Float16 h = (_Float16)x;
    return __builtin_bit_cast(unsigned short, h);
}
__device__ __forceinline__ unsigned int pack2(float x, float y) {
    return (unsigned int)h16(x) | ((unsigned int)h16(y) << 16);
}

// grid 512 x 512 threads, 70,656 B LDS.
// ROUND-7: occupancy model reconciled across R0-R6: CSV VGPR_Count is ARCH
// regs only; acc[8] adds 32 accum regs in the unified file. Total 128+32=160
// -> 12 waves/CU -> a 2nd 8-wave block never fit (R0/R5/R6 all ~19-20% occ).
// launch_bounds 2nd arg is BLOCKS/CU, cap = 2048/(blocks*8): (512,2)->128,
// (512,4)->64 — and the cap math ignores accum regs. Fix:
//   (a) __launch_bounds__(512,3): arch cap ~85; total ~117 <= 128
//       -> 4 waves/SIMD -> 2 blocks/CU genuinely co-schedulable.
//   (b) drop pk0[16]/pk1[16] (32 regs): stream pack2(g[c],g[c+1]) to bufG
//       during the backward recurrence (ds_write_b32 per even step).
// Filter reads post directly from global (512B-coalesced rows, L2/L3
// resident, ~3x redundancy). One barrier per block.
template<bool ATOMIC>
__global__ __launch_bounds__(512, 3)
void stdp_main(const float* __restrict__ pre, const float* __restrict__ post,
               const int* __restrict__ dtp,
               unsigned int* __restrict__ part, float* __restrict__ wpost,
               float* __restrict__ outat)
{
    __shared__ __align__(16) unsigned short bufG[NN * GS];  // 66,560 B g tile
    __shared__ float lds_ps[NWAVE * NN];                    // 4 KB

    const int tid  = threadIdx.x;
    const int bi   = blockIdx.x;
    const int b    = bi >> 5;            // batch (32 chunks of 256 per batch)
    const int ch   = bi & 31;            // chunk index in batch
    const int t00  = ch * CHUNK;
    const int wv   = tid >> 6;           // wave 0..7
    const int lane = tid & 63;

    const float dtf = (float)(*dtp);
    const float r   = expf(-dtf * (1.0f / 20.0f));

    const float* pb = post + (size_t)b * TT * NN;
    const float* ab = pre  + (size_t)b * TT * NN;

    const int q0   = lane * 2;
    const int base = wv * WIN;           // window start (32 steps per wave)
    // P(m) = post[t00 + 1 + m][q0..q0+1]; valid iff m <= mlim
    const float* prow = pb + (size_t)(t00 + 1) * NN + q0;
    const int mlim = TT - 2 - t00;

    // ---------- filter: window WIN=32, 2 q per lane, direct global reads ----------
    float ps0 = 0.f, ps1 = 0.f;
    // Startup g[31] = sum_{tau=1..59} r^tau * P(base+30+tau), 4 strided ILP
    // chains (dep depth 15). Then backward recurrence c=30..0:
    // g[c] = r*(g[c+1] + P(base+c)) - r^60 * P(base+c+59);
    // stream pack2(g[c], g[c+1]) into bufG at even c (g[c+1] kept in gk).
    #define LDF(m) (*(const float2*)(prow + (size_t)(m) * NN))
    #define LDG(m) (((m) <= mlim) ? LDF(m) : make_float2(0.f, 0.f))
    #define FILTER_BODY(LD) {                                                 \
        const float r2 = r * r, r3 = r2 * r, r4 = r2 * r2;                    \
        float2 p = LD(base + 31);                /* tau=1 */                  \
        ps0 += p.x; ps1 += p.y;                                               \
        float gx0 = r  * p.x, gy0 = r  * p.y;                                 \
        p = LD(base + 32);                       /* tau=2 */                  \
        float gx1 = r2 * p.x, gy1 = r2 * p.y;                                 \
        p = LD(base + 33);                       /* tau=3 */                  \
        float gx2 = r3 * p.x, gy2 = r3 * p.y;                                 \
        p = LD(base + 34);                       /* tau=4 */                  \
        float gx3 = r4 * p.x, gy3 = r4 * p.y;                                 \
        float wA = r * r4, wB = r2 * r4, wC = r3 * r4, wD = r4 * r4;          \
        _Pragma("unroll")                                                     \
        for (int j = 1; j < 15; ++j) {                                        \
            p = LD(base + 31 + 4 * j);                                        \
            gx0 = fmaf(wA, p.x, gx0); gy0 = fmaf(wA, p.y, gy0);               \
            p = LD(base + 32 + 4 * j);                                        \
            gx1 = fmaf(wB, p.x, gx1); gy1 = fmaf(wB, p.y, gy1);               \
            p = LD(base + 33 + 4 * j);                                        \
            gx2 = fmaf(wC, p.x, gx2); gy2 = fmaf(wC, p.y, gy2);               \
            if (j < 14) {                                                     \
                p = LD(base + 34 + 4 * j);                                    \
                gx3 = fmaf(wD, p.x, gx3); gy3 = fmaf(wD, p.y, gy3);           \
            }                                                                 \
            wA *= r4; wB *= r4; wC *= r4; wD *= r4;                           \
        }                                                                     \
        const float r8 = r4 * r4, r16 = r8 * r8, r32 = r16 * r16;             \
        const float r60 = ((r32 * r16) * r8) * r4;                            \
        float gx = (gx0 + gx1) + (gx2 + gx3);                                 \
        float gy = (gy0 + gy1) + (gy2 + gy3);                                 \
        float gkx = gx, gky = gy;                 /* g[31] */                 \
        unsigned short* d0 = &bufG[q0 * GS + base];                           \
        unsigned short* d1 = &bufG[(q0 + 1) * GS + base];                     \
        _Pragma("unroll")                                                     \
        for (int c = 30; c >= 0; --c) {                                       \
            const float2 p1  = LD(base + c);                                  \
            const float2 p60 = LD(base + c + 59);                             \
            gx = r * (gx + p1.x) - r60 * p60.x;                               \
            gy = r * (gy + p1.y) - r60 * p60.y;                               \
            ps0 += p1.x; ps1 += p1.y;                                         \
            if (c & 1) {                                                      \
                gkx = gx; gky = gy;                                           \
            } else {                                                          \
                *(unsigned int*)(d0 + c) = pack2(gx, gkx);                    \
                *(unsigned int*)(d1 + c) = pack2(gy, gky);                    \
            }                                                                 \
        }                                                                     \
    }

    if (base + 89 <= mlim) {             // fast path: whole window in-range
        FILTER_BODY(LDF)
    } else {                             // only tail waves of ch==31
        FILTER_BODY(LDG)
    }

    lds_ps[wv * NN + q0]     = ps0;
    lds_ps[wv * NN + q0 + 1] = ps1;
    __syncthreads();                     // the ONLY barrier: g + ps visible

    // ---------- wpost (store overlaps MFMA below) ----------
    if (tid < NN) {
        float s = 0.f;
        #pragma unroll
        for (int w = 0; w < NWAVE; ++w) s += lds_ps[w * NN + tid];
        if (ch == 0) s += pb[tid];       // window (t0, t0+256] misses t=0 once per batch
        if constexpr (ATOMIC) atomicAdd(&wpost[tid], s);
        else wpost[(size_t)bi * NN + tid] = s;
    }

    // ---------- MFMA: wave wv owns pre rows [wv*16, wv*16+16), all 128 q ----------
    const int pr0 = wv * 16;
    f32x4 acc[8];
    #pragma unroll
    for (int qt = 0; qt < 8; ++qt) acc[qt] = (f32x4){0.f, 0.f, 0.f, 0.f};

    {
        const float* abase = ab + (size_t)(t00 + (lane >> 4) * 8) * NN + pr0 + (lane & 15);
        float an[8];
        #pragma unroll
        for (int j = 0; j < 8; ++j) an[j] = abase[(size_t)j * NN];
        #pragma unroll
        for (int ks = 0; ks < 8; ++ks) {
            f16x8 af;
            #pragma unroll
            for (int j = 0; j < 8; ++j) af[j] = (_Float16)an[j];
            if (ks < 7) {
                const float* src = abase + (size_t)((ks + 1) * 32) * NN;
                #pragma unroll
                for (int j = 0; j < 8; ++j) an[j] = src[(size_t)j * NN];
            }
            const int koff = ks * 32 + (lane >> 4) * 8;
            #pragma unroll
            for (int qt = 0; qt < 8; ++qt) {
                const unsigned short* gp = &bufG[(qt * 16 + (lane & 15)) * GS + koff];
                const uint2 lo = *(const uint2*)(gp);
                const uint2 hi = *(const uint2*)(gp + 4);
                const uint4 u  = make_uint4(lo.x, lo.y, hi.x, hi.y);
                const f16x8 bf = __builtin_bit_cast(f16x8, u);
                acc[qt] = __builtin_amdgcn_mfma_f32_16x16x32_f16(af, bf, acc[qt], 0, 0, 0);
            }
        }
    }

    // ---------- write partial: u32-packed f16 pairs, coalesced ----------
    if constexpr (!ATOMIC) {
        unsigned int* dst = part + ((size_t)bi * 8 + wv) * 1024 + lane;
        #pragma unroll
        for (int qt = 0; qt < 8; ++qt) {
            dst[qt * 128]      = pack2(acc[qt][0], acc[qt][1]);
            dst[qt * 128 + 64] = pack2(acc[qt][2], acc[qt][3]);
        }
    } else {
        #pragma unroll
        for (int qt = 0; qt < 8; ++qt)
            #pragma unroll
            for (int rg = 0; rg < 4; ++rg) {
                const int prow_o = pr0 + (lane >> 4) * 4 + rg;
                const int qcol   = qt * 16 + (lane & 15);
                atomicAdd(&outat[prow_o * NN + qcol], acc[qt][rg]);
            }
    }
    #undef FILTER_BODY
    #undef LDF
    #undef LDG
}

// fused split-K reduce + hfac + epilogue: 128 blocks x 512 thr.
// Each block's 64 slots share one qt => 16 distinct q: hfac computed in-kernel.
__global__ __launch_bounds__(512)
void finalize_ws(const unsigned int* __restrict__ part, const float* __restrict__ wpost,
                 const int* __restrict__ dtp, const float* __restrict__ W,
                 float* __restrict__ out)
{
    __shared__ float2 red[512];
    __shared__ float  hfs[16];
    const int s    = threadIdx.x & 63;        // slot within block's 64
    const int kq   = threadIdx.x >> 6;        // 0..7
    const int slot = blockIdx.x * 64 + s;     // 0..8191
    const int qt   = (slot >> 7) & 7;         // fixed for whole block
    const int qbase = qt * 16;

    // hfac: 32 threads per q, shfl reduce over wpost[0..NBLK)[q]
    {
        const int qi = threadIdx.x >> 5;      // 0..15
        const int pr = threadIdx.x & 31;
        float hsum = 0.f;
        const int q = qbase + qi;
        #pragma unroll 4
        for (int k = pr; k < NBLK; k += 32) hsum += wpost[(size_t)k * NN + q];
        #pragma unroll
        for (int off = 16; off; off >>= 1) hsum += __shfl_down(hsum, off, 32);
        if (pr == 0) {
            const float dtf   = (float)(*dtp);
            const float alpha = dtf * 1e-3f;
            hfs[qi] = -0.001f * (alpha * (hsum * (1.0f / (float)(BB * TT)) - 0.1f));
        }
    }

    float sx = 0.f, sy = 0.f;
    #pragma unroll 8
    for (int k = kq * (NBLK / 8); k < (kq + 1) * (NBLK / 8); ++k) {
        const unsigned int v = part[(size_t)k * SLOTS + slot];
        const f16x2 h = __builtin_bit_cast(f16x2, v);
        sx += (float)h[0];
        sy += (float)h[1];
    }
    red[threadIdx.x] = make_float2(sx, sy);
    __syncthreads();
    if (threadIdx.x < 64) {
        float tx = red[s].x, ty = red[s].y;
        #pragma unroll
        for (int g = 1; g < 8; ++g) {
            const float2 v = red[g * 64 + s];
            tx += v.x; ty += v.y;
        }
        // un-permute slot -> (p, q)
        const int lane = slot & 63;
        const int rp   = (slot >> 6) & 1;
        const int wv   = slot >> 10;
        const int p    = wv * 16 + ((lane >> 4) << 2) + rp * 2;
        const int qi   = lane & 15;
        const int q    = qbase + qi;
        const float scale = (float)((0.005 - 0.00525) / (double)(BB * TT));
        const float hf = hfs[qi];
        out[p * NN + q]       = fmaf(tx, scale, hf * W[p * NN + q]);
        out[(p + 1) * NN + q] = fmaf(ty, scale, hf * W[(p + 1) * NN + q]);
    }
}

// fallback epilogue when S was atomically accumulated in d_out
__global__ void finalize_at(const float* __restrict__ wpost, const int* __restrict__ dtp,
                            const float* __restrict__ W, float* __restrict__ out)
{
    const int i = (blockIdx.x * 256 + threadIdx.x) * 2;
    const int q = i & 127;
    const float scale = (float)((0.005 - 0.00525) / (double)(BB * TT));
    const float dtf   = (float)(*dtp);
    const float alpha = dtf * 1e-3f;
    const float inv   = 1.0f / (float)(BB * TT);
    const float hf0   = -0.001f * (alpha * (wpost[q]     * inv - 0.1f));
    const float hf1   = -0.001f * (alpha * (wpost[q + 1] * inv - 0.1f));
    float2 sv = *(const float2*)(out + i);
    float2 w  = *(const float2*)(W + i);
    float2 o;
    o.x = fmaf(sv.x, scale, hf0 * w.x);
    o.y = fmaf(sv.y, scale, hf1 * w.y);
    *(float2*)(out + i) = o;
}

extern "C" void kernel_launch(void* const* d_in, const int* in_sizes, int n_in,
                              void* d_out, int out_size, void* d_ws, size_t ws_size,
                              hipStream_t stream)
{
    const float* pre  = (const float*)d_in[0];
    const float* post = (const float*)d_in[1];
    const float* W    = (const float*)d_in[2];
    const int*   dtp  = (const int*)d_in[3];
    float* out = (float*)d_out;

    const size_t part_bytes  = (size_t)NBLK * SLOTS * sizeof(unsigned int); // 16 MiB
    const size_t wpost_bytes = (size_t)NBLK * NN * sizeof(float);           // 256 KiB
    const size_t need = part_bytes + wpost_bytes;

    if (ws_size >= need) {
        unsigned int* part = (unsigned int*)d_ws;
        float* wpost       = (float*)((char*)d_ws + part_bytes);
        hipLaunchKernelGGL((stdp_main<false>), dim3(NBLK), dim3(512), 0, stream,
                           pre, post, dtp, part, wpost, (float*)nullptr);
        hipLaunchKernelGGL(finalize_ws, dim3(SLOTS / 64), dim3(512), 0, stream,
                           part, wpost, dtp, W, out);
    } else {
        // atomic fallback: needs only 512 B of workspace
        float* wpost = (float*)d_ws;
        hipMemsetAsync(d_out, 0, OUTN * sizeof(float), stream);
        hipMemsetAsync(wpost, 0, NN * sizeof(float), stream);
        hipLaunchKernelGGL((stdp_main<true>), dim3(NBLK), dim3(512), 0, stream,
                           pre, post, dtp, (unsigned int*)nullptr, wpost, out);
        hipLaunchKernelGGL(finalize_at, dim3(OUTN / 512), dim3(256), 0, stream,
                           wpost, dtp, W, out);
    }
}

// Round 8
// 170.572 us; speedup vs baseline: 1.0580x; 1.0580x over previous
//
#include <hip/hip_runtime.h>

#define BB 16
#define TT 8192
#define NN 128                     // N_PRE == N_POST
constexpr int CHUNK = 256;         // time-steps per block (1 chunk per block)
constexpr int NBLK  = BB * TT / CHUNK;   // 512 blocks
constexpr int OUTN  = NN * NN;           // 16384
constexpr int GS    = 260;         // bufG row stride in halves (520 B, 8B-aligned)
constexpr int SLOTS = OUTN / 2;    // 8192 packed u32 slots per block-slice
constexpr int NWAVE = 8;           // 512 threads

typedef _Float16 f16x8 __attribute__((ext_vector_type(8)));
typedef _Float16 f16x2 __attribute__((ext_vector_type(2)));
typedef float    f32x4 __attribute__((ext_vector_type(4)));

__device__ __forceinline__ unsigned short h16(float x) {
    _Float16 h = (_Float16)x;
    return __builtin_bit_cast(unsigned short, h);
}
__device__ __forceinline__ unsigned int pack2(float x, float y) {
    return (unsigned int)h16(x) | ((unsigned int)h16(y) << 16);
}

// ROUND-8: filter moved onto the MFMA pipe (it idled at ~2.5% for 7 rounds;
// the VALU filter's 58-deep recurrence + serial loads were the latency bind).
// g = W_T · P, W_T[c,m] = r^(m-c+1) on band 0<=m-c<=58, banded Toeplitz:
//  - A-fragments of W_T depend only on (m_tile - t_tile) in {-16,0,16,32,48,64}
//    -> 6 constant f16x8 fragments built once from expf (r^tau in [0.052,0.95],
//    f16-normal, ~5e-4 rel err).
//  - band -> 3 MFMAs per 16x16 G-tile (K=96 window); 16 tiles/wave = 48 MFMAs
//    replace ~400 dependent VALU ops + serial recurrence.
//  - P fragments loaded direct from global f32->f16; sliding window reuses
//    2/3 fragments per step -> 10 fragment loads (80 dwords)/wave ~= 1x P.
//  - G accum layout (col=lane&15=q, row=(lane>>4)*4+reg=c) lands transposed
//    exactly for bufG[q][t]: one 8B ds_write per tile.
// Occupancy lesson (R0-R7): 2nd launch_bounds arg -> VGPR cap = 256/arg;
// a 2nd 512-thr block never co-schedules regardless -> stop chasing it;
// (512,2) = cap 128 = proven no-spill.
template<bool ATOMIC>
__global__ __launch_bounds__(512, 2)
void stdp_main(const float* __restrict__ pre, const float* __restrict__ post,
               const int* __restrict__ dtp,
               unsigned int* __restrict__ part, float* __restrict__ wpost,
               float* __restrict__ outat)
{
    __shared__ __align__(16) unsigned short bufG[NN * GS];  // 66,560 B g tile
    __shared__ float lds_ps[NWAVE * NN];                    // 4 KB

    const int tid  = threadIdx.x;
    const int bi   = blockIdx.x;
    const int b    = bi >> 5;            // batch (32 chunks of 256 per batch)
    const int ch   = bi & 31;            // chunk index in batch
    const int t00  = ch * CHUNK;
    const int wv   = tid >> 6;           // wave 0..7
    const int lane = tid & 63;
    const int cl   = lane & 15;          // MFMA row/col lane index
    const int kg   = lane >> 4;          // MFMA k-subgroup (0..3)

    const float dtf = (float)(*dtp);
    const float lw  = -dtf * (1.0f / 20.0f);   // log(r)

    const float* pb = post + (size_t)b * TT * NN;
    const float* ab = pre  + (size_t)b * TT * NN;

    // valid P(m) = post[t00+1+m] iff m <= mlim
    const int mlim = TT - 2 - t00;

    // ---------- build the 6 Toeplitz W fragments (once) ----------
    // variant vi: V = vi*16 - 16; lane holds W[c=tb+cl][m=tb+V+kk], kk=kg*8+j
    // value = r^(d+1) for d = V+kk-cl in [0,58], else 0.
    f16x8 wf[6];
    #pragma unroll
    for (int vi = 0; vi < 6; ++vi) {
        const int V = vi * 16 - 16;
        #pragma unroll
        for (int j = 0; j < 8; ++j) {
            const int d = V + kg * 8 + j - cl;
            wf[vi][j] = (d >= 0 && d <= 58) ? (_Float16)__expf(lw * (float)(d + 1))
                                            : (_Float16)0.0f;
        }
    }

    // ---------- filter: wave wv owns q-block qb, 16 t-tiles x 3 MFMA ----------
    const int qb = wv * 16;
    const float* pbase = pb + (size_t)(t00 + 1) * NN + qb + cl;

    #define LOADFRAG(dstf, M) {                                               \
        const float* p0_ = pbase + (size_t)((M) + kg * 8) * NN;               \
        if ((M) + 31 <= mlim) {                                               \
            _Pragma("unroll")                                                 \
            for (int j = 0; j < 8; ++j) dstf[j] = (_Float16)p0_[(size_t)j * NN]; \
        } else {                                                              \
            _Pragma("unroll")                                                 \
            for (int j = 0; j < 8; ++j) {                                     \
                const int m_ = (M) + kg * 8 + j;                              \
                dstf[j] = (m_ <= mlim) ? (_Float16)p0_[(size_t)j * NN]        \
                                       : (_Float16)0.0f;                      \
            }                                                                 \
        }                                                                     \
    }

    {
        f16x8 fr0, fr1, fr2;
        LOADFRAG(fr0, 0)
        LOADFRAG(fr1, 32)
        LOADFRAG(fr2, 64)
        #pragma unroll
        for (int s = 0; s < 16; ++s) {
            const int tb = s * 16;
            if (s >= 2 && (s & 1) == 0) {       // window slides by 32
                fr0 = fr1; fr1 = fr2;
                LOADFRAG(fr2, tb + 64)
            }
            f32x4 g = (f32x4){0.f, 0.f, 0.f, 0.f};
            if (s & 1) {                         // base = tb-16: V=-16,16,48
                g = __builtin_amdgcn_mfma_f32_16x16x32_f16(wf[0], fr0, g, 0, 0, 0);
                g = __builtin_amdgcn_mfma_f32_16x16x32_f16(wf[2], fr1, g, 0, 0, 0);
                g = __builtin_amdgcn_mfma_f32_16x16x32_f16(wf[4], fr2, g, 0, 0, 0);
            } else {                             // base = tb: V=0,32,64
                g = __builtin_amdgcn_mfma_f32_16x16x32_f16(wf[1], fr0, g, 0, 0, 0);
                g = __builtin_amdgcn_mfma_f32_16x16x32_f16(wf[3], fr1, g, 0, 0, 0);
                g = __builtin_amdgcn_mfma_f32_16x16x32_f16(wf[5], fr2, g, 0, 0, 0);
            }
            // C layout: col=cl=q, row=kg*4+reg=c  ->  bufG[q][t], 8B store
            *(uint2*)&bufG[(qb + cl) * GS + tb + kg * 4] =
                make_uint2(pack2(g[0], g[1]), pack2(g[2], g[3]));
        }
    }
    #undef LOADFRAG

    // ---------- ps: column sums of P over this wave's 32 rows ----------
    {
        float ps0 = 0.f, ps1 = 0.f;
        const float* pr2 = pb + (size_t)(t00 + 1) * NN + lane * 2;
        #pragma unroll
        for (int i = 0; i < 32; ++i) {
            const int m = wv * 32 + i;
            if (ch != 31 || m <= mlim) {        // wave-uniform guard
                const float2 v = *(const float2*)(pr2 + (size_t)m * NN);
                ps0 += v.x; ps1 += v.y;
            }
        }
        lds_ps[wv * NN + lane * 2]     = ps0;
        lds_ps[wv * NN + lane * 2 + 1] = ps1;
    }
    __syncthreads();                     // the ONLY barrier: g + ps visible

    // ---------- wpost (store overlaps MFMA below) ----------
    if (tid < NN) {
        float s = 0.f;
        #pragma unroll
        for (int w = 0; w < NWAVE; ++w) s += lds_ps[w * NN + tid];
        if (ch == 0) s += pb[tid];       // window (t0, t0+256] misses t=0 once per batch
        if constexpr (ATOMIC) atomicAdd(&wpost[tid], s);
        else wpost[(size_t)bi * NN + tid] = s;
    }

    // ---------- main GEMM: wave wv owns pre rows [wv*16, wv*16+16), all 128 q ----------
    const int pr0 = wv * 16;
    f32x4 acc[8];
    #pragma unroll
    for (int qt = 0; qt < 8; ++qt) acc[qt] = (f32x4){0.f, 0.f, 0.f, 0.f};

    {
        const float* abase = ab + (size_t)(t00 + kg * 8) * NN + pr0 + cl;
        float an[8];
        #pragma unroll
        for (int j = 0; j < 8; ++j) an[j] = abase[(size_t)j * NN];
        #pragma unroll
        for (int ks = 0; ks < 8; ++ks) {
            f16x8 af;
            #pragma unroll
            for (int j = 0; j < 8; ++j) af[j] = (_Float16)an[j];
            if (ks < 7) {
                const float* src = abase + (size_t)((ks + 1) * 32) * NN;
                #pragma unroll
                for (int j = 0; j < 8; ++j) an[j] = src[(size_t)j * NN];
            }
            const int koff = ks * 32 + kg * 8;
            #pragma unroll
            for (int qt = 0; qt < 8; ++qt) {
                const unsigned short* gp = &bufG[(qt * 16 + cl) * GS + koff];
                const uint2 lo = *(const uint2*)(gp);
                const uint2 hi = *(const uint2*)(gp + 4);
                const uint4 u  = make_uint4(lo.x, lo.y, hi.x, hi.y);
                const f16x8 bf = __builtin_bit_cast(f16x8, u);
                acc[qt] = __builtin_amdgcn_mfma_f32_16x16x32_f16(af, bf, acc[qt], 0, 0, 0);
            }
        }
    }

    // ---------- write partial: u32-packed f16 pairs, coalesced ----------
    if constexpr (!ATOMIC) {
        unsigned int* dst = part + ((size_t)bi * 8 + wv) * 1024 + lane;
        #pragma unroll
        for (int qt = 0; qt < 8; ++qt) {
            dst[qt * 128]      = pack2(acc[qt][0], acc[qt][1]);
            dst[qt * 128 + 64] = pack2(acc[qt][2], acc[qt][3]);
        }
    } else {
        #pragma unroll
        for (int qt = 0; qt < 8; ++qt)
            #pragma unroll
            for (int rg = 0; rg < 4; ++rg) {
                const int prow_o = pr0 + kg * 4 + rg;
                const int qcol   = qt * 16 + cl;
                atomicAdd(&outat[prow_o * NN + qcol], acc[qt][rg]);
            }
    }
}

// fused split-K reduce + hfac + epilogue: 128 blocks x 512 thr.
// Each block's 64 slots share one qt => 16 distinct q: hfac computed in-kernel.
__global__ __launch_bounds__(512)
void finalize_ws(const unsigned int* __restrict__ part, const float* __restrict__ wpost,
                 const int* __restrict__ dtp, const float* __restrict__ W,
                 float* __restrict__ out)
{
    __shared__ float2 red[512];
    __shared__ float  hfs[16];
    const int s    = threadIdx.x & 63;        // slot within block's 64
    const int kq   = threadIdx.x >> 6;        // 0..7
    const int slot = blockIdx.x * 64 + s;     // 0..8191
    const int qt   = (slot >> 7) & 7;         // fixed for whole block
    const int qbase = qt * 16;

    // hfac: 32 threads per q, shfl reduce over wpost[0..NBLK)[q]
    {
        const int qi = threadIdx.x >> 5;      // 0..15
        const int pr = threadIdx.x & 31;
        float hsum = 0.f;
        const int q = qbase + qi;
        #pragma unroll 4
        for (int k = pr; k < NBLK; k += 32) hsum += wpost[(size_t)k * NN + q];
        #pragma unroll
        for (int off = 16; off; off >>= 1) hsum += __shfl_down(hsum, off, 32);
        if (pr == 0) {
            const float dtf   = (float)(*dtp);
            const float alpha = dtf * 1e-3f;
            hfs[qi] = -0.001f * (alpha * (hsum * (1.0f / (float)(BB * TT)) - 0.1f));
        }
    }

    float sx = 0.f, sy = 0.f;
    #pragma unroll 8
    for (int k = kq * (NBLK / 8); k < (kq + 1) * (NBLK / 8); ++k) {
        const unsigned int v = part[(size_t)k * SLOTS + slot];
        const f16x2 h = __builtin_bit_cast(f16x2, v);
        sx += (float)h[0];
        sy += (float)h[1];
    }
    red[threadIdx.x] = make_float2(sx, sy);
    __syncthreads();
    if (threadIdx.x < 64) {
        float tx = red[s].x, ty = red[s].y;
        #pragma unroll
        for (int g = 1; g < 8; ++g) {
            const float2 v = red[g * 64 + s];
            tx += v.x; ty += v.y;
        }
        // un-permute slot -> (p, q)
        const int lane = slot & 63;
        const int rp   = (slot >> 6) & 1;
        const int wv   = slot >> 10;
        const int p    = wv * 16 + ((lane >> 4) << 2) + rp * 2;
        const int qi   = lane & 15;
        const int q    = qbase + qi;
        const float scale = (float)((0.005 - 0.00525) / (double)(BB * TT));
        const float hf = hfs[qi];
        out[p * NN + q]       = fmaf(tx, scale, hf * W[p * NN + q]);
        out[(p + 1) * NN + q] = fmaf(ty, scale, hf * W[(p + 1) * NN + q]);
    }
}

// fallback epilogue when S was atomically accumulated in d_out
__global__ void finalize_at(const float* __restrict__ wpost, const int* __restrict__ dtp,
                            const float* __restrict__ W, float* __restrict__ out)
{
    const int i = (blockIdx.x * 256 + threadIdx.x) * 2;
    const int q = i & 127;
    const float scale = (float)((0.005 - 0.00525) / (double)(BB * TT));
    const float dtf   = (float)(*dtp);
    const float alpha = dtf * 1e-3f;
    const float inv   = 1.0f / (float)(BB * TT);
    const float hf0   = -0.001f * (alpha * (wpost[q]     * inv - 0.1f));
    const float hf1   = -0.001f * (alpha * (wpost[q + 1] * inv - 0.1f));
    float2 sv = *(const float2*)(out + i);
    float2 w  = *(const float2*)(W + i);
    float2 o;
    o.x = fmaf(sv.x, scale, hf0 * w.x);
    o.y = fmaf(sv.y, scale, hf1 * w.y);
    *(float2*)(out + i) = o;
}

extern "C" void kernel_launch(void* const* d_in, const int* in_sizes, int n_in,
                              void* d_out, int out_size, void* d_ws, size_t ws_size,
                              hipStream_t stream)
{
    const float* pre  = (const float*)d_in[0];
    const float* post = (const float*)d_in[1];
    const float* W    = (const float*)d_in[2];
    const int*   dtp  = (const int*)d_in[3];
    float* out = (float*)d_out;

    const size_t part_bytes  = (size_t)NBLK * SLOTS * sizeof(unsigned int); // 16 MiB
    const size_t wpost_bytes = (size_t)NBLK * NN * sizeof(float);           // 256 KiB
    const size_t need = part_bytes + wpost_bytes;

    if (ws_size >= need) {
        unsigned int* part = (unsigned int*)d_ws;
        float* wpost       = (float*)((char*)d_ws + part_bytes);
        hipLaunchKernelGGL((stdp_main<false>), dim3(NBLK), dim3(512), 0, stream,
                           pre, post, dtp, part, wpost, (float*)nullptr);
        hipLaunchKernelGGL(finalize_ws, dim3(SLOTS / 64), dim3(512), 0, stream,
                           part, wpost, dtp, W, out);
    } else {
        // atomic fallback: needs only 512 B of workspace
        float* wpost = (float*)d_ws;
        hipMemsetAsync(d_out, 0, OUTN * sizeof(float), stream);
        hipMemsetAsync(wpost, 0, NN * sizeof(float), stream);
        hipLaunchKernelGGL((stdp_main<true>), dim3(NBLK), dim3(512), 0, stream,
                           pre, post, dtp, (unsigned int*)nullptr, wpost, out);
        hipLaunchKernelGGL(finalize_at, dim3(OUTN / 512), dim3(256), 0, stream,
                           wpost, dtp, W, out);
    }
}